// Round 5
// baseline (632.268 us; speedup 1.0000x reference)
//
#include <hip/hip_runtime.h>
#include <hip/hip_bf16.h>
#include <math.h>

#define NN 50000
#define EE 800000
#define HC 128
#define FF 32
#define NEG 0.2f

// ---------------- CSR build ----------------

__global__ void k_hist(const int* __restrict__ dst, int* __restrict__ deg) {
    int e = blockIdx.x * 256 + threadIdx.x;
    if (e < EE) atomicAdd(&deg[dst[e]], 1);
}

// single-block chunked exclusive scan of deg -> rowptr
__global__ __launch_bounds__(256) void k_scan(const int* __restrict__ deg,
                                              int* __restrict__ rowptr) {
    __shared__ int sums[256];
    const int t = threadIdx.x;
    const int CH = (NN + 255) >> 8;           // 196
    const int b0 = t * CH;
    const int b1 = b0 + CH < NN ? b0 + CH : NN;
    int s = 0;
    for (int i = b0; i < b1; ++i) s += deg[i];
    sums[t] = s;
    __syncthreads();
    int acc = s;
    for (int off = 1; off < 256; off <<= 1) {
        int tmp = (t >= off) ? sums[t - off] : 0;
        __syncthreads();
        acc += tmp;
        sums[t] = acc;
        __syncthreads();
    }
    int run = acc - s;                         // exclusive prefix
    for (int i = b0; i < b1; ++i) { rowptr[i] = run; run += deg[i]; }
    if (t == 255) rowptr[NN] = EE;
}

__global__ void k_scatter(const int* __restrict__ src, const int* __restrict__ dst,
                          const float* __restrict__ ea, const int* __restrict__ rowptr,
                          int* __restrict__ fill, int2* __restrict__ pairs) {
    int e = blockIdx.x * 256 + threadIdx.x;
    if (e >= EE) return;
    int d = dst[e];
    int pos = rowptr[d] + atomicAdd(&fill[d], 1);
    pairs[pos] = make_int2(src[e], __float_as_int(fabsf(ea[e])));
}

// ---------------- dual linear: xl = x@Wl+bl, xr = x@Wr+br ----------------
// One wave per node. Lane l: half=l>>5 (xl/xr), cols 4*(l&31)..+3 with weights
// in 128 VGPRs. x row (8 quads) loaded replicated every 8 lanes, broadcast via
// width-8 shfl: 32 shfl + 128 wave-FMA per node.

__global__ __launch_bounds__(256) void k_dual_linear(
        const float* __restrict__ x,
        const float* __restrict__ Wl, const float* __restrict__ bl,
        const float* __restrict__ Wr, const float* __restrict__ br,
        float* __restrict__ xl, float* __restrict__ xr) {
    const int t = threadIdx.x;
    const int l = t & 63;
    const int half = l >> 5;
    const int lc = l & 31;
    const float* __restrict__ W  = half ? Wr : Wl;
    const float* __restrict__ bb = half ? br : bl;
    float* __restrict__ outp     = half ? xr : xl;

    float4 w[32];
#pragma unroll
    for (int k = 0; k < 32; ++k)
        w[k] = *(const float4*)(W + k * 128 + 4 * lc);
    const float4 bias = *(const float4*)(bb + 4 * lc);

    const int gw = blockIdx.x * 4 + (t >> 6);
    const int nW = gridDim.x * 4;
    const int q8 = 4 * (l & 7);

    int n = gw;
    if (n >= NN) return;
    float4 r0 = *(const float4*)(x + (size_t)n * 32 + q8);
    int n1 = n + nW < NN ? n + nW : n;
    float4 r1 = *(const float4*)(x + (size_t)n1 * 32 + q8);

    for (; n < NN; n += nW) {
        float4 cur = r0;
        r0 = r1;
        int np = n + 2 * nW < NN ? n + 2 * nW : n;
        r1 = *(const float4*)(x + (size_t)np * 32 + q8);

        float4 acc = bias;
#pragma unroll
        for (int q = 0; q < 8; ++q) {
            float vx = __shfl(cur.x, q, 8);
            float vy = __shfl(cur.y, q, 8);
            float vz = __shfl(cur.z, q, 8);
            float vw = __shfl(cur.w, q, 8);
            acc.x = fmaf(vx, w[4 * q + 0].x, acc.x);
            acc.y = fmaf(vx, w[4 * q + 0].y, acc.y);
            acc.z = fmaf(vx, w[4 * q + 0].z, acc.z);
            acc.w = fmaf(vx, w[4 * q + 0].w, acc.w);
            acc.x = fmaf(vy, w[4 * q + 1].x, acc.x);
            acc.y = fmaf(vy, w[4 * q + 1].y, acc.y);
            acc.z = fmaf(vy, w[4 * q + 1].z, acc.z);
            acc.w = fmaf(vy, w[4 * q + 1].w, acc.w);
            acc.x = fmaf(vz, w[4 * q + 2].x, acc.x);
            acc.y = fmaf(vz, w[4 * q + 2].y, acc.y);
            acc.z = fmaf(vz, w[4 * q + 2].z, acc.z);
            acc.w = fmaf(vz, w[4 * q + 2].w, acc.w);
            acc.x = fmaf(vw, w[4 * q + 3].x, acc.x);
            acc.y = fmaf(vw, w[4 * q + 3].y, acc.y);
            acc.z = fmaf(vw, w[4 * q + 3].z, acc.z);
            acc.w = fmaf(vw, w[4 * q + 3].w, acc.w);
        }
        *(float4*)(outp + (size_t)n * 128 + 4 * lc) = acc;
    }
}

// ---------------- fused GATv2 edge-softmax + aggregate (single pass) ----------------
// 32 threads per dst node (float4 = 4 channels each), 8 nodes per 256-block.
// Branchless flash-style online softmax; 32-bit byte-offset addressing;
// clamped prefetch (pairs depth-3, xl depth-2), unroll 2.

__global__ __launch_bounds__(256) void k_gat_agg(
        const float* __restrict__ xl, const float* __restrict__ xr,
        const int* __restrict__ rowptr, const int2* __restrict__ pairs,
        const float* __restrict__ att,   // [128]
        const float* __restrict__ Wev,   // [128]
        const float* __restrict__ cb,    // [128]
        float* __restrict__ outb) {
    const int l = threadIdx.x & 31;
    const int n = blockIdx.x * 8 + (threadIdx.x >> 5);
    const char* __restrict__ xlp = (const char*)xl + (l << 4);  // per-lane base

    float4 att4 = ((const float4*)att)[l];
    float4 we4  = ((const float4*)Wev)[l];
    float4 xr4  = ((const float4*)xr)[n * 32 + l];
    const int beg = rowptr[n], end = rowptr[n + 1];
    const int last = end - 1;

    float m = -INFINITY, s = 0.f;
    float4 acc = make_float4(0.f, 0.f, 0.f, 0.f);

    if (beg < end) {
        int2 p0 = pairs[beg];
        int2 p1 = pairs[beg + 1 < last ? beg + 1 : last];
        int2 p2 = pairs[beg + 2 < last ? beg + 2 : last];
        float4 x0 = *(const float4*)(xlp + (p0.x << 9));
        float4 x1 = *(const float4*)(xlp + (p1.x << 9));

#pragma unroll 2
        for (int j = beg; j <= last; ++j) {
            int jn = j + 3 < last ? j + 3 : last;
            int2 pn = pairs[jn];
            float4 xn = *(const float4*)(xlp + (p2.x << 9));

            float sea = __int_as_float(p0.y);
            float4 v;
            v.x = fmaf(sea, we4.x, xr4.x + x0.x);
            v.y = fmaf(sea, we4.y, xr4.y + x0.y);
            v.z = fmaf(sea, we4.z, xr4.z + x0.z);
            v.w = fmaf(sea, we4.w, xr4.w + x0.w);
            v.x = fmaxf(v.x, NEG * v.x);
            v.y = fmaxf(v.y, NEG * v.y);
            v.z = fmaxf(v.z, NEG * v.z);
            v.w = fmaxf(v.w, NEG * v.w);
            float pl = v.x * att4.x;
            pl = fmaf(v.y, att4.y, pl);
            pl = fmaf(v.z, att4.z, pl);
            pl = fmaf(v.w, att4.w, pl);
            pl += __shfl_xor(pl, 4);
            pl += __shfl_xor(pl, 2);
            pl += __shfl_xor(pl, 1);

            float mn = fmaxf(m, pl);
            float c  = __expf(m - mn);    // 1 when max unchanged, 0 on first iter
            float e  = __expf(pl - mn);
            s = fmaf(s, c, e);
            acc.x = fmaf(acc.x, c, e * x0.x);
            acc.y = fmaf(acc.y, c, e * x0.y);
            acc.z = fmaf(acc.z, c, e * x0.z);
            acc.w = fmaf(acc.w, c, e * x0.w);
            m = mn;

            p0 = p1; p1 = p2; p2 = pn;
            x0 = x1; x1 = xn;
        }
    }

    float inv = (s > 0.f) ? 1.f / s : 0.f;
    float4 cb4 = ((const float4*)cb)[l];
    float4 o;
    o.x = fmaf(acc.x, inv, cb4.x);
    o.y = fmaf(acc.y, inv, cb4.y);
    o.z = fmaf(acc.z, inv, cb4.z);
    o.w = fmaf(acc.w, inv, cb4.w);
    ((float4*)outb)[n * 32 + l] = o;
}

// ---------------- per-node MLP + BN: h = leaky(out@lW+lb)*bsc+bsh ----------------

__global__ __launch_bounds__(256) void k_mlp_bn(
        const float* __restrict__ outb,
        const float* __restrict__ lW, const float* __restrict__ lb,
        const float* __restrict__ bsc, const float* __restrict__ bsh,
        float* __restrict__ h) {
    const int t = threadIdx.x;
    const int l = t & 63;
    const int half = l >> 5;
    const int cg = (l >> 2) & 7;
    const int kg = l & 3;

    float4 w[32];
#pragma unroll
    for (int kl = 0; kl < 32; ++kl)
        w[kl] = *(const float4*)(lW + (size_t)(32 * kg + kl) * 32 + 4 * cg);

    const float4 bias = (kg == 0) ? *(const float4*)(lb + 4 * cg)
                                  : make_float4(0.f, 0.f, 0.f, 0.f);
    const float4 sc4 = *(const float4*)(bsc + 4 * cg);
    const float4 sh4 = *(const float4*)(bsh + 4 * cg);

    const int gw = blockIdx.x * 4 + (t >> 6);
    const int nW = gridDim.x * 4;
    const int quad = 4 * (l & 31);
    const int kg8 = kg * 8;

    int p = gw;
    if (p >= NN / 2) return;
    float4 r0 = *(const float4*)(outb + (size_t)(2 * p + half) * 128 + quad);
    int p1i = p + nW < NN / 2 ? p + nW : p;
    float4 r1 = *(const float4*)(outb + (size_t)(2 * p1i + half) * 128 + quad);

    for (; p < NN / 2; p += nW) {
        float4 cur = r0;
        r0 = r1;
        int pp = p + 2 * nW < NN / 2 ? p + 2 * nW : p;
        r1 = *(const float4*)(outb + (size_t)(2 * pp + half) * 128 + quad);

        float4 acc = bias;
#pragma unroll
        for (int j = 0; j < 8; ++j) {
            float vx = __shfl(cur.x, kg8 + j, 32);
            float vy = __shfl(cur.y, kg8 + j, 32);
            float vz = __shfl(cur.z, kg8 + j, 32);
            float vw = __shfl(cur.w, kg8 + j, 32);
            acc.x = fmaf(vx, w[4 * j + 0].x, acc.x);
            acc.y = fmaf(vx, w[4 * j + 0].y, acc.y);
            acc.z = fmaf(vx, w[4 * j + 0].z, acc.z);
            acc.w = fmaf(vx, w[4 * j + 0].w, acc.w);
            acc.x = fmaf(vy, w[4 * j + 1].x, acc.x);
            acc.y = fmaf(vy, w[4 * j + 1].y, acc.y);
            acc.z = fmaf(vy, w[4 * j + 1].z, acc.z);
            acc.w = fmaf(vy, w[4 * j + 1].w, acc.w);
            acc.x = fmaf(vz, w[4 * j + 2].x, acc.x);
            acc.y = fmaf(vz, w[4 * j + 2].y, acc.y);
            acc.z = fmaf(vz, w[4 * j + 2].z, acc.z);
            acc.w = fmaf(vz, w[4 * j + 2].w, acc.w);
            acc.x = fmaf(vw, w[4 * j + 3].x, acc.x);
            acc.y = fmaf(vw, w[4 * j + 3].y, acc.y);
            acc.z = fmaf(vw, w[4 * j + 3].z, acc.z);
            acc.w = fmaf(vw, w[4 * j + 3].w, acc.w);
        }
        acc.x += __shfl_xor(acc.x, 1); acc.x += __shfl_xor(acc.x, 2);
        acc.y += __shfl_xor(acc.y, 1); acc.y += __shfl_xor(acc.y, 2);
        acc.z += __shfl_xor(acc.z, 1); acc.z += __shfl_xor(acc.z, 2);
        acc.w += __shfl_xor(acc.w, 1); acc.w += __shfl_xor(acc.w, 2);

        if (kg == 0) {
            float4 o;
            o.x = fmaxf(acc.x, NEG * acc.x);
            o.y = fmaxf(acc.y, NEG * acc.y);
            o.z = fmaxf(acc.z, NEG * acc.z);
            o.w = fmaxf(acc.w, NEG * acc.w);
            o.x = fmaf(o.x, sc4.x, sh4.x);
            o.y = fmaf(o.y, sc4.y, sh4.y);
            o.z = fmaf(o.z, sc4.z, sh4.z);
            o.w = fmaf(o.w, sc4.w, sh4.w);
            *(float4*)(h + (size_t)(2 * p + half) * 32 + 4 * cg) = o;
        }
    }
}

// ---------------- global mean pool: per-block partial column sums ----------------

__global__ void k_colsum(const float* __restrict__ h, float* __restrict__ part_g) {
    __shared__ float sd[256];
    int t = threadIdx.x;
    int col = t & 31, r = t >> 5;
    float local = 0.f;
    for (int row = blockIdx.x * 8 + r; row < NN; row += gridDim.x * 8)
        local += h[row * FF + col];
    sd[t] = local; __syncthreads();
    if (r < 4) sd[t] += sd[t + 128];
    __syncthreads();
    if (r < 2) sd[t] += sd[t + 64];
    __syncthreads();
    if (r < 1) part_g[blockIdx.x * 32 + col] = sd[t] + sd[t + 32];
}

// ---------------- head MLP: reduce partials; 32 -> 256 -> 32 -> 2 ----------------

__global__ void k_head(const float* __restrict__ part_g,   // [128][32]
                       const float* __restrict__ W1, const float* __restrict__ b1,
                       const float* __restrict__ W2, const float* __restrict__ b2,
                       const float* __restrict__ W3, const float* __restrict__ b3,
                       float* __restrict__ out) {
    __shared__ float red[256];
    __shared__ float gv[32];
    __shared__ float h1[256];
    __shared__ float h2[32];
    int t = threadIdx.x;
    int col = t & 31, r = t >> 5;
    float lsum = 0.f;
#pragma unroll
    for (int k = 0; k < 16; ++k) lsum += part_g[(r + 8 * k) * 32 + col];
    red[t] = lsum; __syncthreads();
    if (r < 4) red[t] += red[t + 128];
    __syncthreads();
    if (r < 2) red[t] += red[t + 64];
    __syncthreads();
    if (r < 1) gv[col] = (red[t] + red[t + 32]) * (1.0f / NN);
    __syncthreads();
    float acc = b1[t];
#pragma unroll 8
    for (int k = 0; k < 32; ++k) acc += gv[k] * W1[k * 256 + t];
    h1[t] = acc > 0.f ? acc : NEG * acc;
    __syncthreads();
    if (t < 32) {
        float a = b2[t];
        for (int k = 0; k < 256; ++k) a += h1[k] * W2[k * 32 + t];
        h2[t] = a > 0.f ? a : NEG * a;
    }
    __syncthreads();
    if (t < 2) {
        float a = b3[t];
#pragma unroll
        for (int k = 0; k < 32; ++k) a += h2[k] * W3[k * 2 + t];
        out[t] = a;
    }
}

// ---------------- host ----------------

static inline size_t alignup(size_t x) { return (x + 255) & ~size_t(255); }

extern "C" void kernel_launch(void* const* d_in, const int* in_sizes, int n_in,
                              void* d_out, int out_size, void* d_ws, size_t ws_size,
                              hipStream_t stream) {
    const float* x     = (const float*)d_in[0];
    const int*   eidx  = (const int*)d_in[1];
    const float* eattr = (const float*)d_in[2];
    const float* Wl    = (const float*)d_in[4];
    const float* bl    = (const float*)d_in[5];
    const float* Wr    = (const float*)d_in[6];
    const float* br    = (const float*)d_in[7];
    const float* att   = (const float*)d_in[8];
    const float* We    = (const float*)d_in[9];
    const float* cb    = (const float*)d_in[10];
    const float* lW    = (const float*)d_in[11];
    const float* lb    = (const float*)d_in[12];
    const float* bsc   = (const float*)d_in[13];
    const float* bsh   = (const float*)d_in[14];
    const float* W1    = (const float*)d_in[15];
    const float* b1    = (const float*)d_in[16];
    const float* W2    = (const float*)d_in[17];
    const float* b2    = (const float*)d_in[18];
    const float* W3    = (const float*)d_in[19];
    const float* b3    = (const float*)d_in[20];

    const int* srcp = eidx;
    const int* dstp = eidx + EE;

    char* ws = (char*)d_ws;
    size_t off = 0;
    float* xl     = (float*)(ws + off); off += alignup((size_t)NN * HC * 4);
    float* xr     = (float*)(ws + off); off += alignup((size_t)NN * HC * 4);
    float* outb   = (float*)(ws + off); off += alignup((size_t)NN * HC * 4);
    float* hA     = (float*)(ws + off); off += alignup((size_t)NN * FF * 4);
    float* hB     = (float*)(ws + off); off += alignup((size_t)NN * FF * 4);
    int2*  pairs  = (int2*) (ws + off); off += alignup((size_t)EE * 8);
    int*   rowptr = (int*)  (ws + off); off += alignup((size_t)(NN + 1) * 4);
    int*   deg    = (int*)  (ws + off); off += alignup((size_t)NN * 4);
    int*   fill   = (int*)  (ws + off); off += alignup((size_t)NN * 4);
    float* part_g = (float*)(ws + off); off += alignup(128 * 32 * 4);

    // one memset covers deg + fill (adjacent, incl. align padding)
    hipMemsetAsync(deg, 0, alignup((size_t)NN * 4) + (size_t)NN * 4, stream);

    k_hist<<<(EE + 255) / 256, 256, 0, stream>>>(dstp, deg);
    k_scan<<<1, 256, 0, stream>>>(deg, rowptr);
    k_scatter<<<(EE + 255) / 256, 256, 0, stream>>>(srcp, dstp, eattr, rowptr, fill, pairs);

    const float* cur = x;
    float* hbuf[2] = {hA, hB};
    for (int i = 0; i < 3; ++i) {
        k_dual_linear<<<768, 256, 0, stream>>>(cur, Wl + i * FF * HC, bl + i * HC,
                                               Wr + i * FF * HC, br + i * HC, xl, xr);
        k_gat_agg<<<NN / 8, 256, 0, stream>>>(xl, xr, rowptr, pairs,
                                              att + i * HC, We + i * HC, cb + i * HC, outb);
        k_mlp_bn<<<768, 256, 0, stream>>>(outb, lW + i * HC * FF, lb + i * FF,
                                          bsc + i * FF, bsh + i * FF, hbuf[i & 1]);
        cur = hbuf[i & 1];
    }

    k_colsum<<<128, 256, 0, stream>>>(cur, part_g);
    k_head<<<1, 256, 0, stream>>>(part_g, W1, b1, W2, b2, W3, b3, (float*)d_out);
}

// Round 6
// 513.767 us; speedup vs baseline: 1.2307x; 1.2307x over previous
//
#include <hip/hip_runtime.h>
#include <hip/hip_bf16.h>
#include <math.h>

#define NN 50000
#define EE 800000
#define HC 128
#define FF 32
#define NEG 0.2f
#define CAP 64
#define LOG2E 1.4426950408889634f

// ---------------- bucket build (no hist/scan needed: max degree << CAP) ----------------

__global__ void k_bucket(const int* __restrict__ src, const int* __restrict__ dst,
                         const float* __restrict__ ea, int* __restrict__ cnt,
                         int2* __restrict__ pairs) {
    int e = blockIdx.x * 256 + threadIdx.x;
    if (e >= EE) return;
    int d = dst[e];
    int pos = atomicAdd(&cnt[d], 1);
    pairs[d * CAP + pos] = make_int2(src[e], __float_as_int(fabsf(ea[e])));
}

// ---------------- CSR fallback path (if ws too small for buckets) ----------------

__global__ void k_hist(const int* __restrict__ dst, int* __restrict__ deg) {
    int e = blockIdx.x * 256 + threadIdx.x;
    if (e < EE) atomicAdd(&deg[dst[e]], 1);
}

__global__ void k_scan1(const int* __restrict__ deg, int* __restrict__ part) {
    __shared__ int sd[256];
    int b = blockIdx.x, t = threadIdx.x;
    int base = b * 1024 + t * 4;
    int s = 0;
#pragma unroll
    for (int i = 0; i < 4; ++i) { int idx = base + i; if (idx < NN) s += deg[idx]; }
    sd[t] = s; __syncthreads();
    for (int off = 128; off; off >>= 1) { if (t < off) sd[t] += sd[t + off]; __syncthreads(); }
    if (t == 0) part[b] = sd[0];
}

__global__ void k_scan2(int* __restrict__ part, int nb) {
    if (threadIdx.x == 0) {
        int run = 0;
        for (int i = 0; i < nb; ++i) { int v = part[i]; part[i] = run; run += v; }
    }
}

__global__ void k_scan3(const int* __restrict__ deg, const int* __restrict__ part,
                        int* __restrict__ rowptr) {
    __shared__ int sd[256];
    int b = blockIdx.x, t = threadIdx.x;
    int base = b * 1024 + t * 4;
    int v[4]; int mine = 0;
#pragma unroll
    for (int i = 0; i < 4; ++i) { int idx = base + i; v[i] = (idx < NN) ? deg[idx] : 0; mine += v[i]; }
    sd[t] = mine; __syncthreads();
    for (int off = 1; off < 256; off <<= 1) {
        int tmp = (t >= off) ? sd[t - off] : 0;
        __syncthreads();
        sd[t] += tmp;
        __syncthreads();
    }
    int run = sd[t] - mine + part[b];
#pragma unroll
    for (int i = 0; i < 4; ++i) { int idx = base + i; if (idx < NN) rowptr[idx] = run; run += v[i]; }
    if (b == 0 && t == 0) rowptr[NN] = EE;
}

__global__ void k_scatter(const int* __restrict__ src, const int* __restrict__ dst,
                          const float* __restrict__ ea, const int* __restrict__ rowptr,
                          int* __restrict__ fill, int2* __restrict__ pairs) {
    int e = blockIdx.x * 256 + threadIdx.x;
    if (e >= EE) return;
    int d = dst[e];
    int pos = rowptr[d] + atomicAdd(&fill[d], 1);
    pairs[pos] = make_int2(src[e], __float_as_int(fabsf(ea[e])));
}

// ---------------- dual linear: xl = x@Wl+bl, xr = x@Wr+br ----------------

__global__ __launch_bounds__(256) void k_dual_linear(
        const float* __restrict__ x,
        const float* __restrict__ Wl, const float* __restrict__ bl,
        const float* __restrict__ Wr, const float* __restrict__ br,
        float* __restrict__ xl, float* __restrict__ xr) {
    const int t = threadIdx.x;
    const int l = t & 63;
    const int half = l >> 5;
    const int lc = l & 31;
    const float* __restrict__ W  = half ? Wr : Wl;
    const float* __restrict__ bb = half ? br : bl;
    float* __restrict__ outp     = half ? xr : xl;

    float4 w[32];
#pragma unroll
    for (int k = 0; k < 32; ++k)
        w[k] = *(const float4*)(W + k * 128 + 4 * lc);
    const float4 bias = *(const float4*)(bb + 4 * lc);

    const int gw = blockIdx.x * 4 + (t >> 6);
    const int nW = gridDim.x * 4;
    const int q8 = 4 * (l & 7);

    int n = gw;
    if (n >= NN) return;
    float4 r0 = *(const float4*)(x + (size_t)n * 32 + q8);
    int n1 = n + nW < NN ? n + nW : n;
    float4 r1 = *(const float4*)(x + (size_t)n1 * 32 + q8);

    for (; n < NN; n += nW) {
        float4 cur = r0;
        r0 = r1;
        int np = n + 2 * nW < NN ? n + 2 * nW : n;
        r1 = *(const float4*)(x + (size_t)np * 32 + q8);

        float4 acc = bias;
#pragma unroll
        for (int q = 0; q < 8; ++q) {
            float vx = __shfl(cur.x, q, 8);
            float vy = __shfl(cur.y, q, 8);
            float vz = __shfl(cur.z, q, 8);
            float vw = __shfl(cur.w, q, 8);
            acc.x = fmaf(vx, w[4 * q + 0].x, acc.x);
            acc.y = fmaf(vx, w[4 * q + 0].y, acc.y);
            acc.z = fmaf(vx, w[4 * q + 0].z, acc.z);
            acc.w = fmaf(vx, w[4 * q + 0].w, acc.w);
            acc.x = fmaf(vy, w[4 * q + 1].x, acc.x);
            acc.y = fmaf(vy, w[4 * q + 1].y, acc.y);
            acc.z = fmaf(vy, w[4 * q + 1].z, acc.z);
            acc.w = fmaf(vy, w[4 * q + 1].w, acc.w);
            acc.x = fmaf(vz, w[4 * q + 2].x, acc.x);
            acc.y = fmaf(vz, w[4 * q + 2].y, acc.y);
            acc.z = fmaf(vz, w[4 * q + 2].z, acc.z);
            acc.w = fmaf(vz, w[4 * q + 2].w, acc.w);
            acc.x = fmaf(vw, w[4 * q + 3].x, acc.x);
            acc.y = fmaf(vw, w[4 * q + 3].y, acc.y);
            acc.z = fmaf(vw, w[4 * q + 3].z, acc.z);
            acc.w = fmaf(vw, w[4 * q + 3].w, acc.w);
        }
        *(float4*)(outp + (size_t)n * 128 + 4 * lc) = acc;
    }
}

// ---------------- fused GATv2 edge-softmax + aggregate (single pass) ----------------
// 32 threads per dst node (float4 = 4 channels each), 8 nodes per 256-block.
// Branchless flash softmax in log2 domain (att pre-scaled by log2(e));
// 32-bit byte-offset addressing; clamped prefetch; unroll 2.

template<bool BUCKET>
__global__ __launch_bounds__(256) void k_gat_agg(
        const float* __restrict__ xl, const float* __restrict__ xr,
        const int* __restrict__ idx,     // BUCKET: cnt[N]; CSR: rowptr[N+1]
        const int2* __restrict__ pairs,
        const float* __restrict__ att,   // [128]
        const float* __restrict__ Wev,   // [128]
        const float* __restrict__ cb,    // [128]
        float* __restrict__ outb) {
    const int l = threadIdx.x & 31;
    const int n = blockIdx.x * 8 + (threadIdx.x >> 5);
    const char* __restrict__ xlp = (const char*)xl + (l << 4);  // per-lane base

    float4 att4 = ((const float4*)att)[l];
    att4.x *= LOG2E; att4.y *= LOG2E; att4.z *= LOG2E; att4.w *= LOG2E;
    float4 we4  = ((const float4*)Wev)[l];
    float4 xr4  = ((const float4*)xr)[n * 32 + l];
    int beg, end;
    if (BUCKET) { beg = n * CAP; end = beg + idx[n]; }
    else        { beg = idx[n];  end = idx[n + 1]; }
    const int last = end - 1;

    float m = -INFINITY, s = 0.f;
    float4 acc = make_float4(0.f, 0.f, 0.f, 0.f);

    if (beg < end) {
        int2 p0 = pairs[beg];
        int2 p1 = pairs[beg + 1 < last ? beg + 1 : last];
        int2 p2 = pairs[beg + 2 < last ? beg + 2 : last];
        float4 x0 = *(const float4*)(xlp + (p0.x << 9));
        float4 x1 = *(const float4*)(xlp + (p1.x << 9));

#pragma unroll 2
        for (int j = beg; j <= last; ++j) {
            int jn = j + 3 < last ? j + 3 : last;
            int2 pn = pairs[jn];
            float4 xn = *(const float4*)(xlp + (p2.x << 9));

            float sea = __int_as_float(p0.y);
            float4 v;
            v.x = fmaf(sea, we4.x, xr4.x + x0.x);
            v.y = fmaf(sea, we4.y, xr4.y + x0.y);
            v.z = fmaf(sea, we4.z, xr4.z + x0.z);
            v.w = fmaf(sea, we4.w, xr4.w + x0.w);
            v.x = fmaxf(v.x, NEG * v.x);
            v.y = fmaxf(v.y, NEG * v.y);
            v.z = fmaxf(v.z, NEG * v.z);
            v.w = fmaxf(v.w, NEG * v.w);
            float pl = v.x * att4.x;              // pl in log2 units
            pl = fmaf(v.y, att4.y, pl);
            pl = fmaf(v.z, att4.z, pl);
            pl = fmaf(v.w, att4.w, pl);
            pl += __shfl_xor(pl, 4);
            pl += __shfl_xor(pl, 2);
            pl += __shfl_xor(pl, 1);

            float mn = fmaxf(m, pl);
            float c  = __builtin_amdgcn_exp2f(m - mn);
            float e  = __builtin_amdgcn_exp2f(pl - mn);
            s = fmaf(s, c, e);
            acc.x = fmaf(acc.x, c, e * x0.x);
            acc.y = fmaf(acc.y, c, e * x0.y);
            acc.z = fmaf(acc.z, c, e * x0.z);
            acc.w = fmaf(acc.w, c, e * x0.w);
            m = mn;

            p0 = p1; p1 = p2; p2 = pn;
            x0 = x1; x1 = xn;
        }
    }

    float inv = (s > 0.f) ? 1.f / s : 0.f;
    float4 cb4 = ((const float4*)cb)[l];
    float4 o;
    o.x = fmaf(acc.x, inv, cb4.x);
    o.y = fmaf(acc.y, inv, cb4.y);
    o.z = fmaf(acc.z, inv, cb4.z);
    o.w = fmaf(acc.w, inv, cb4.w);
    ((float4*)outb)[n * 32 + l] = o;
}

// ---------------- per-node MLP + BN: h = leaky(out@lW+lb)*bsc+bsh ----------------

__global__ __launch_bounds__(256) void k_mlp_bn(
        const float* __restrict__ outb,
        const float* __restrict__ lW, const float* __restrict__ lb,
        const float* __restrict__ bsc, const float* __restrict__ bsh,
        float* __restrict__ h) {
    const int t = threadIdx.x;
    const int l = t & 63;
    const int half = l >> 5;
    const int cg = (l >> 2) & 7;
    const int kg = l & 3;

    float4 w[32];
#pragma unroll
    for (int kl = 0; kl < 32; ++kl)
        w[kl] = *(const float4*)(lW + (size_t)(32 * kg + kl) * 32 + 4 * cg);

    const float4 bias = (kg == 0) ? *(const float4*)(lb + 4 * cg)
                                  : make_float4(0.f, 0.f, 0.f, 0.f);
    const float4 sc4 = *(const float4*)(bsc + 4 * cg);
    const float4 sh4 = *(const float4*)(bsh + 4 * cg);

    const int gw = blockIdx.x * 4 + (t >> 6);
    const int nW = gridDim.x * 4;
    const int quad = 4 * (l & 31);
    const int kg8 = kg * 8;

    int p = gw;
    if (p >= NN / 2) return;
    float4 r0 = *(const float4*)(outb + (size_t)(2 * p + half) * 128 + quad);
    int p1i = p + nW < NN / 2 ? p + nW : p;
    float4 r1 = *(const float4*)(outb + (size_t)(2 * p1i + half) * 128 + quad);

    for (; p < NN / 2; p += nW) {
        float4 cur = r0;
        r0 = r1;
        int pp = p + 2 * nW < NN / 2 ? p + 2 * nW : p;
        r1 = *(const float4*)(outb + (size_t)(2 * pp + half) * 128 + quad);

        float4 acc = bias;
#pragma unroll
        for (int j = 0; j < 8; ++j) {
            float vx = __shfl(cur.x, kg8 + j, 32);
            float vy = __shfl(cur.y, kg8 + j, 32);
            float vz = __shfl(cur.z, kg8 + j, 32);
            float vw = __shfl(cur.w, kg8 + j, 32);
            acc.x = fmaf(vx, w[4 * j + 0].x, acc.x);
            acc.y = fmaf(vx, w[4 * j + 0].y, acc.y);
            acc.z = fmaf(vx, w[4 * j + 0].z, acc.z);
            acc.w = fmaf(vx, w[4 * j + 0].w, acc.w);
            acc.x = fmaf(vy, w[4 * j + 1].x, acc.x);
            acc.y = fmaf(vy, w[4 * j + 1].y, acc.y);
            acc.z = fmaf(vy, w[4 * j + 1].z, acc.z);
            acc.w = fmaf(vy, w[4 * j + 1].w, acc.w);
            acc.x = fmaf(vz, w[4 * j + 2].x, acc.x);
            acc.y = fmaf(vz, w[4 * j + 2].y, acc.y);
            acc.z = fmaf(vz, w[4 * j + 2].z, acc.z);
            acc.w = fmaf(vz, w[4 * j + 2].w, acc.w);
            acc.x = fmaf(vw, w[4 * j + 3].x, acc.x);
            acc.y = fmaf(vw, w[4 * j + 3].y, acc.y);
            acc.z = fmaf(vw, w[4 * j + 3].z, acc.z);
            acc.w = fmaf(vw, w[4 * j + 3].w, acc.w);
        }
        acc.x += __shfl_xor(acc.x, 1); acc.x += __shfl_xor(acc.x, 2);
        acc.y += __shfl_xor(acc.y, 1); acc.y += __shfl_xor(acc.y, 2);
        acc.z += __shfl_xor(acc.z, 1); acc.z += __shfl_xor(acc.z, 2);
        acc.w += __shfl_xor(acc.w, 1); acc.w += __shfl_xor(acc.w, 2);

        if (kg == 0) {
            float4 o;
            o.x = fmaxf(acc.x, NEG * acc.x);
            o.y = fmaxf(acc.y, NEG * acc.y);
            o.z = fmaxf(acc.z, NEG * acc.z);
            o.w = fmaxf(acc.w, NEG * acc.w);
            o.x = fmaf(o.x, sc4.x, sh4.x);
            o.y = fmaf(o.y, sc4.y, sh4.y);
            o.z = fmaf(o.z, sc4.z, sh4.z);
            o.w = fmaf(o.w, sc4.w, sh4.w);
            *(float4*)(h + (size_t)(2 * p + half) * 32 + 4 * cg) = o;
        }
    }
}

// ---------------- global mean pool: per-block partial column sums ----------------

__global__ void k_colsum(const float* __restrict__ h, float* __restrict__ part_g) {
    __shared__ float sd[256];
    int t = threadIdx.x;
    int col = t & 31, r = t >> 5;
    float local = 0.f;
    for (int row = blockIdx.x * 8 + r; row < NN; row += gridDim.x * 8)
        local += h[row * FF + col];
    sd[t] = local; __syncthreads();
    if (r < 4) sd[t] += sd[t + 128];
    __syncthreads();
    if (r < 2) sd[t] += sd[t + 64];
    __syncthreads();
    if (r < 1) part_g[blockIdx.x * 32 + col] = sd[t] + sd[t + 32];
}

// ---------------- head MLP: reduce partials; 32 -> 256 -> 32 -> 2 ----------------

__global__ void k_head(const float* __restrict__ part_g,   // [128][32]
                       const float* __restrict__ W1, const float* __restrict__ b1,
                       const float* __restrict__ W2, const float* __restrict__ b2,
                       const float* __restrict__ W3, const float* __restrict__ b3,
                       float* __restrict__ out) {
    __shared__ float red[256];
    __shared__ float gv[32];
    __shared__ float h1[256];
    __shared__ float h2[32];
    int t = threadIdx.x;
    int col = t & 31, r = t >> 5;
    float lsum = 0.f;
#pragma unroll
    for (int k = 0; k < 16; ++k) lsum += part_g[(r + 8 * k) * 32 + col];
    red[t] = lsum; __syncthreads();
    if (r < 4) red[t] += red[t + 128];
    __syncthreads();
    if (r < 2) red[t] += red[t + 64];
    __syncthreads();
    if (r < 1) gv[col] = (red[t] + red[t + 32]) * (1.0f / NN);
    __syncthreads();
    float acc = b1[t];
#pragma unroll 8
    for (int k = 0; k < 32; ++k) acc += gv[k] * W1[k * 256 + t];
    h1[t] = acc > 0.f ? acc : NEG * acc;
    __syncthreads();
    if (t < 32) {
        float a = b2[t];
        for (int k = 0; k < 256; ++k) a += h1[k] * W2[k * 32 + t];
        h2[t] = a > 0.f ? a : NEG * a;
    }
    __syncthreads();
    if (t < 2) {
        float a = b3[t];
#pragma unroll
        for (int k = 0; k < 32; ++k) a += h2[k] * W3[k * 2 + t];
        out[t] = a;
    }
}

// ---------------- host ----------------

static inline size_t alignup(size_t x) { return (x + 255) & ~size_t(255); }

extern "C" void kernel_launch(void* const* d_in, const int* in_sizes, int n_in,
                              void* d_out, int out_size, void* d_ws, size_t ws_size,
                              hipStream_t stream) {
    const float* x     = (const float*)d_in[0];
    const int*   eidx  = (const int*)d_in[1];
    const float* eattr = (const float*)d_in[2];
    const float* Wl    = (const float*)d_in[4];
    const float* bl    = (const float*)d_in[5];
    const float* Wr    = (const float*)d_in[6];
    const float* br    = (const float*)d_in[7];
    const float* att   = (const float*)d_in[8];
    const float* We    = (const float*)d_in[9];
    const float* cb    = (const float*)d_in[10];
    const float* lW    = (const float*)d_in[11];
    const float* lb    = (const float*)d_in[12];
    const float* bsc   = (const float*)d_in[13];
    const float* bsh   = (const float*)d_in[14];
    const float* W1    = (const float*)d_in[15];
    const float* b1    = (const float*)d_in[16];
    const float* W2    = (const float*)d_in[17];
    const float* b2    = (const float*)d_in[18];
    const float* W3    = (const float*)d_in[19];
    const float* b3    = (const float*)d_in[20];

    const int* srcp = eidx;
    const int* dstp = eidx + EE;

    char* ws = (char*)d_ws;
    size_t off = 0;
    float* xl     = (float*)(ws + off); off += alignup((size_t)NN * HC * 4);
    float* xr     = (float*)(ws + off); off += alignup((size_t)NN * HC * 4);
    float* outb   = (float*)(ws + off); off += alignup((size_t)NN * HC * 4);
    float* hA     = (float*)(ws + off); off += alignup((size_t)NN * FF * 4);
    float* hB     = (float*)(ws + off); off += alignup((size_t)NN * FF * 4);
    float* part_g = (float*)(ws + off); off += alignup(128 * 32 * 4);

    // bucket layout
    size_t boff = off;
    int2*  pairsB = (int2*)(ws + boff); boff += alignup((size_t)NN * CAP * 8);
    int*   cntB   = (int*) (ws + boff); boff += alignup((size_t)NN * 4);
    const bool bucket = (ws_size >= boff);

    const float* cur = x;
    float* hbuf[2] = {hA, hB};

    if (bucket) {
        hipMemsetAsync(cntB, 0, (size_t)NN * 4, stream);
        k_bucket<<<(EE + 255) / 256, 256, 0, stream>>>(srcp, dstp, eattr, cntB, pairsB);
        for (int i = 0; i < 3; ++i) {
            k_dual_linear<<<768, 256, 0, stream>>>(cur, Wl + i * FF * HC, bl + i * HC,
                                                   Wr + i * FF * HC, br + i * HC, xl, xr);
            k_gat_agg<true><<<NN / 8, 256, 0, stream>>>(xl, xr, cntB, pairsB,
                                                        att + i * HC, We + i * HC,
                                                        cb + i * HC, outb);
            k_mlp_bn<<<768, 256, 0, stream>>>(outb, lW + i * HC * FF, lb + i * FF,
                                              bsc + i * FF, bsh + i * FF, hbuf[i & 1]);
            cur = hbuf[i & 1];
        }
    } else {
        // CSR fallback: hist + 3-kernel scan + scatter
        size_t coff = off;
        int2* pairsC  = (int2*)(ws + coff); coff += alignup((size_t)EE * 8);
        int*  rowptr  = (int*) (ws + coff); coff += alignup((size_t)(NN + 1) * 4);
        int*  deg     = (int*) (ws + coff); coff += alignup((size_t)NN * 4);
        int*  fill    = (int*) (ws + coff); coff += alignup((size_t)NN * 4);
        int*  part    = (int*) (ws + coff); coff += alignup(64 * 4);

        hipMemsetAsync(deg, 0, alignup((size_t)NN * 4) + (size_t)NN * 4, stream);
        const int nChunk = (NN + 1023) / 1024;  // 49
        k_hist<<<(EE + 255) / 256, 256, 0, stream>>>(dstp, deg);
        k_scan1<<<nChunk, 256, 0, stream>>>(deg, part);
        k_scan2<<<1, 64, 0, stream>>>(part, nChunk);
        k_scan3<<<nChunk, 256, 0, stream>>>(deg, part, rowptr);
        k_scatter<<<(EE + 255) / 256, 256, 0, stream>>>(srcp, dstp, eattr, rowptr, fill, pairsC);

        for (int i = 0; i < 3; ++i) {
            k_dual_linear<<<768, 256, 0, stream>>>(cur, Wl + i * FF * HC, bl + i * HC,
                                                   Wr + i * FF * HC, br + i * HC, xl, xr);
            k_gat_agg<false><<<NN / 8, 256, 0, stream>>>(xl, xr, rowptr, pairsC,
                                                         att + i * HC, We + i * HC,
                                                         cb + i * HC, outb);
            k_mlp_bn<<<768, 256, 0, stream>>>(outb, lW + i * HC * FF, lb + i * FF,
                                              bsc + i * FF, bsh + i * FF, hbuf[i & 1]);
            cur = hbuf[i & 1];
        }
    }

    k_colsum<<<128, 256, 0, stream>>>(cur, part_g);
    k_head<<<1, 256, 0, stream>>>(part_g, W1, b1, W2, b2, W3, b3, (float*)d_out);
}

// Round 7
// 465.592 us; speedup vs baseline: 1.3580x; 1.1035x over previous
//
#include <hip/hip_runtime.h>
#include <hip/hip_bf16.h>
#include <math.h>

#define NN 50000
#define EE 800000
#define HC 128
#define FF 32
#define NEG 0.2f
#define CAP 64
#define LOG2E 1.4426950408889634f

// ---------------- bucket build (no hist/scan: max degree << CAP) ----------------

__global__ void k_bucket(const int* __restrict__ src, const int* __restrict__ dst,
                         const float* __restrict__ ea, int* __restrict__ cnt,
                         int2* __restrict__ pairs) {
    int e = blockIdx.x * 256 + threadIdx.x;
    if (e >= EE) return;
    int d = dst[e];
    int pos = atomicAdd(&cnt[d], 1);
    pairs[d * CAP + pos] = make_int2(src[e], __float_as_int(fabsf(ea[e])));
}

// ---------------- CSR fallback path ----------------

__global__ void k_hist(const int* __restrict__ dst, int* __restrict__ deg) {
    int e = blockIdx.x * 256 + threadIdx.x;
    if (e < EE) atomicAdd(&deg[dst[e]], 1);
}

__global__ void k_scan1(const int* __restrict__ deg, int* __restrict__ part) {
    __shared__ int sd[256];
    int b = blockIdx.x, t = threadIdx.x;
    int base = b * 1024 + t * 4;
    int s = 0;
#pragma unroll
    for (int i = 0; i < 4; ++i) { int idx = base + i; if (idx < NN) s += deg[idx]; }
    sd[t] = s; __syncthreads();
    for (int off = 128; off; off >>= 1) { if (t < off) sd[t] += sd[t + off]; __syncthreads(); }
    if (t == 0) part[b] = sd[0];
}

__global__ void k_scan2(int* __restrict__ part, int nb) {
    if (threadIdx.x == 0) {
        int run = 0;
        for (int i = 0; i < nb; ++i) { int v = part[i]; part[i] = run; run += v; }
    }
}

__global__ void k_scan3(const int* __restrict__ deg, const int* __restrict__ part,
                        int* __restrict__ rowptr) {
    __shared__ int sd[256];
    int b = blockIdx.x, t = threadIdx.x;
    int base = b * 1024 + t * 4;
    int v[4]; int mine = 0;
#pragma unroll
    for (int i = 0; i < 4; ++i) { int idx = base + i; v[i] = (idx < NN) ? deg[idx] : 0; mine += v[i]; }
    sd[t] = mine; __syncthreads();
    for (int off = 1; off < 256; off <<= 1) {
        int tmp = (t >= off) ? sd[t - off] : 0;
        __syncthreads();
        sd[t] += tmp;
        __syncthreads();
    }
    int run = sd[t] - mine + part[b];
#pragma unroll
    for (int i = 0; i < 4; ++i) { int idx = base + i; if (idx < NN) rowptr[idx] = run; run += v[i]; }
    if (b == 0 && t == 0) rowptr[NN] = EE;
}

__global__ void k_scatter(const int* __restrict__ src, const int* __restrict__ dst,
                          const float* __restrict__ ea, const int* __restrict__ rowptr,
                          int* __restrict__ fill, int2* __restrict__ pairs) {
    int e = blockIdx.x * 256 + threadIdx.x;
    if (e >= EE) return;
    int d = dst[e];
    int pos = rowptr[d] + atomicAdd(&fill[d], 1);
    pairs[pos] = make_int2(src[e], __float_as_int(fabsf(ea[e])));
}

// ---------------- dual linear: xl = x@Wl+bl, xr = x@Wr+br ----------------

__global__ __launch_bounds__(256) void k_dual_linear(
        const float* __restrict__ x,
        const float* __restrict__ Wl, const float* __restrict__ bl,
        const float* __restrict__ Wr, const float* __restrict__ br,
        float* __restrict__ xl, float* __restrict__ xr) {
    const int t = threadIdx.x;
    const int l = t & 63;
    const int half = l >> 5;
    const int lc = l & 31;
    const float* __restrict__ W  = half ? Wr : Wl;
    const float* __restrict__ bb = half ? br : bl;
    float* __restrict__ outp     = half ? xr : xl;

    float4 w[32];
#pragma unroll
    for (int k = 0; k < 32; ++k)
        w[k] = *(const float4*)(W + k * 128 + 4 * lc);
    const float4 bias = *(const float4*)(bb + 4 * lc);

    const int gw = blockIdx.x * 4 + (t >> 6);
    const int nW = gridDim.x * 4;
    const int q8 = 4 * (l & 7);

    int n = gw;
    if (n >= NN) return;
    float4 r0 = *(const float4*)(x + (size_t)n * 32 + q8);
    int n1 = n + nW < NN ? n + nW : n;
    float4 r1 = *(const float4*)(x + (size_t)n1 * 32 + q8);

    for (; n < NN; n += nW) {
        float4 cur = r0;
        r0 = r1;
        int np = n + 2 * nW < NN ? n + 2 * nW : n;
        r1 = *(const float4*)(x + (size_t)np * 32 + q8);

        float4 acc = bias;
#pragma unroll
        for (int q = 0; q < 8; ++q) {
            float vx = __shfl(cur.x, q, 8);
            float vy = __shfl(cur.y, q, 8);
            float vz = __shfl(cur.z, q, 8);
            float vw = __shfl(cur.w, q, 8);
            acc.x = fmaf(vx, w[4 * q + 0].x, acc.x);
            acc.y = fmaf(vx, w[4 * q + 0].y, acc.y);
            acc.z = fmaf(vx, w[4 * q + 0].z, acc.z);
            acc.w = fmaf(vx, w[4 * q + 0].w, acc.w);
            acc.x = fmaf(vy, w[4 * q + 1].x, acc.x);
            acc.y = fmaf(vy, w[4 * q + 1].y, acc.y);
            acc.z = fmaf(vy, w[4 * q + 1].z, acc.z);
            acc.w = fmaf(vy, w[4 * q + 1].w, acc.w);
            acc.x = fmaf(vz, w[4 * q + 2].x, acc.x);
            acc.y = fmaf(vz, w[4 * q + 2].y, acc.y);
            acc.z = fmaf(vz, w[4 * q + 2].z, acc.z);
            acc.w = fmaf(vz, w[4 * q + 2].w, acc.w);
            acc.x = fmaf(vw, w[4 * q + 3].x, acc.x);
            acc.y = fmaf(vw, w[4 * q + 3].y, acc.y);
            acc.z = fmaf(vw, w[4 * q + 3].z, acc.z);
            acc.w = fmaf(vw, w[4 * q + 3].w, acc.w);
        }
        *(float4*)(outp + (size_t)n * 128 + 4 * lc) = acc;
    }
}

// ---------------- fused GATv2 edge-softmax + aggregate + MLP/BN (+pool) ----------------
// 32 lanes per dst node, 8 nodes per 256-block. Single-pass branchless flash
// softmax (one exp2 per edge). Epilogue applies the per-layer Linear+LeakyReLU+BN
// using LDS-staged weights with the standalone mlp_bn's (half,cg,kg) wave layout
// (identical math). LAST: skip h store, LDS-accumulate column sums and atomically
// add into 64-way-spread part_g.

template<bool BUCKET, bool LAST>
__global__ __launch_bounds__(256) void k_gat_mlp(
        const float* __restrict__ xl, const float* __restrict__ xr,
        const int* __restrict__ idx,     // BUCKET: cnt[N]; CSR: rowptr[N+1]
        const int2* __restrict__ pairs,
        const float* __restrict__ att,   // [128]
        const float* __restrict__ Wev,   // [128]
        const float* __restrict__ cb,    // [128]
        const float* __restrict__ lW,    // [128][32]
        const float* __restrict__ lb,    // [32]
        const float* __restrict__ bsc, const float* __restrict__ bsh,
        float* __restrict__ hout,        // [N][32] (unused if LAST)
        float* __restrict__ part_g) {    // [64][32] (used if LAST)
    __shared__ float sW[HC * FF];        // 16 KB
    __shared__ float gp[FF];
    {
        float4* d4 = (float4*)sW;
        const float4* s4 = (const float4*)lW;
        for (int i = threadIdx.x; i < HC * FF / 4; i += 256) d4[i] = s4[i];
        if (LAST && threadIdx.x < 32) gp[threadIdx.x] = 0.f;
    }
    __syncthreads();

    const int l = threadIdx.x & 31;
    const int n = blockIdx.x * 8 + (threadIdx.x >> 5);
    const char* __restrict__ xlp = (const char*)xl + (l << 4);  // per-lane base

    float4 att4 = ((const float4*)att)[l];
    att4.x *= LOG2E; att4.y *= LOG2E; att4.z *= LOG2E; att4.w *= LOG2E;
    float4 we4  = ((const float4*)Wev)[l];
    float4 xr4  = ((const float4*)xr)[n * 32 + l];
    int beg, end;
    if (BUCKET) { beg = n * CAP; end = beg + idx[n]; }
    else        { beg = idx[n];  end = idx[n + 1]; }
    const int last = end - 1;

    float m = -INFINITY, s = 0.f;
    float4 acc = make_float4(0.f, 0.f, 0.f, 0.f);

    if (beg < end) {
        int2 p0 = pairs[beg];
        int2 p1 = pairs[beg + 1 < last ? beg + 1 : last];
        int2 p2 = pairs[beg + 2 < last ? beg + 2 : last];
        float4 x0 = *(const float4*)(xlp + (p0.x << 9));
        float4 x1 = *(const float4*)(xlp + (p1.x << 9));

#pragma unroll 2
        for (int j = beg; j <= last; ++j) {
            int jn = j + 3 < last ? j + 3 : last;
            int2 pn = pairs[jn];
            float4 xn = *(const float4*)(xlp + (p2.x << 9));

            float sea = __int_as_float(p0.y);
            float4 v;
            v.x = fmaf(sea, we4.x, xr4.x + x0.x);
            v.y = fmaf(sea, we4.y, xr4.y + x0.y);
            v.z = fmaf(sea, we4.z, xr4.z + x0.z);
            v.w = fmaf(sea, we4.w, xr4.w + x0.w);
            v.x = fmaxf(v.x, NEG * v.x);
            v.y = fmaxf(v.y, NEG * v.y);
            v.z = fmaxf(v.z, NEG * v.z);
            v.w = fmaxf(v.w, NEG * v.w);
            float pl = v.x * att4.x;              // log2 units
            pl = fmaf(v.y, att4.y, pl);
            pl = fmaf(v.z, att4.z, pl);
            pl = fmaf(v.w, att4.w, pl);
            pl += __shfl_xor(pl, 4);
            pl += __shfl_xor(pl, 2);
            pl += __shfl_xor(pl, 1);

            float mn = fmaxf(m, pl);
            float d  = __builtin_amdgcn_exp2f(fminf(m, pl) - mn);
            bool up  = pl > m;                    // exactly one of c,e is 1
            float c  = up ? d : 1.0f;
            float e  = up ? 1.0f : d;
            s = fmaf(s, c, e);
            acc.x = fmaf(acc.x, c, e * x0.x);
            acc.y = fmaf(acc.y, c, e * x0.y);
            acc.z = fmaf(acc.z, c, e * x0.z);
            acc.w = fmaf(acc.w, c, e * x0.w);
            m = mn;

            p0 = p1; p1 = p2; p2 = pn;
            x0 = x1; x1 = xn;
        }
    }

    float inv = (s > 0.f) ? 1.f / s : 0.f;
    float4 cb4 = ((const float4*)cb)[l];
    float4 o;
    o.x = fmaf(acc.x, inv, cb4.x);
    o.y = fmaf(acc.y, inv, cb4.y);
    o.z = fmaf(acc.z, inv, cb4.z);
    o.w = fmaf(acc.w, inv, cb4.w);

    // ---- fused MLP+BN epilogue (same math/layout as standalone k_mlp_bn) ----
    const int cg = (l >> 2) & 7;
    const int kg = l & 3;
    const int kg8 = kg * 8;
    float4 a2 = (kg == 0) ? *(const float4*)(lb + 4 * cg)
                          : make_float4(0.f, 0.f, 0.f, 0.f);
#pragma unroll
    for (int j = 0; j < 8; ++j) {
        float vx = __shfl(o.x, kg8 + j, 32);
        float vy = __shfl(o.y, kg8 + j, 32);
        float vz = __shfl(o.z, kg8 + j, 32);
        float vw = __shfl(o.w, kg8 + j, 32);
        const float* wp = sW + (32 * kg + 4 * j) * 32 + 4 * cg;
        float4 w0 = *(const float4*)(wp);
        float4 w1 = *(const float4*)(wp + 32);
        float4 w2 = *(const float4*)(wp + 64);
        float4 w3 = *(const float4*)(wp + 96);
        a2.x = fmaf(vx, w0.x, a2.x); a2.y = fmaf(vx, w0.y, a2.y);
        a2.z = fmaf(vx, w0.z, a2.z); a2.w = fmaf(vx, w0.w, a2.w);
        a2.x = fmaf(vy, w1.x, a2.x); a2.y = fmaf(vy, w1.y, a2.y);
        a2.z = fmaf(vy, w1.z, a2.z); a2.w = fmaf(vy, w1.w, a2.w);
        a2.x = fmaf(vz, w2.x, a2.x); a2.y = fmaf(vz, w2.y, a2.y);
        a2.z = fmaf(vz, w2.z, a2.z); a2.w = fmaf(vz, w2.w, a2.w);
        a2.x = fmaf(vw, w3.x, a2.x); a2.y = fmaf(vw, w3.y, a2.y);
        a2.z = fmaf(vw, w3.z, a2.z); a2.w = fmaf(vw, w3.w, a2.w);
    }
    a2.x += __shfl_xor(a2.x, 1); a2.x += __shfl_xor(a2.x, 2);
    a2.y += __shfl_xor(a2.y, 1); a2.y += __shfl_xor(a2.y, 2);
    a2.z += __shfl_xor(a2.z, 1); a2.z += __shfl_xor(a2.z, 2);
    a2.w += __shfl_xor(a2.w, 1); a2.w += __shfl_xor(a2.w, 2);

    if (kg == 0) {
        const float4 sc4 = *(const float4*)(bsc + 4 * cg);
        const float4 sh4 = *(const float4*)(bsh + 4 * cg);
        float4 hq;
        hq.x = fmaxf(a2.x, NEG * a2.x);
        hq.y = fmaxf(a2.y, NEG * a2.y);
        hq.z = fmaxf(a2.z, NEG * a2.z);
        hq.w = fmaxf(a2.w, NEG * a2.w);
        hq.x = fmaf(hq.x, sc4.x, sh4.x);
        hq.y = fmaf(hq.y, sc4.y, sh4.y);
        hq.z = fmaf(hq.z, sc4.z, sh4.z);
        hq.w = fmaf(hq.w, sc4.w, sh4.w);
        if (LAST) {
            atomicAdd(&gp[4 * cg + 0], hq.x);
            atomicAdd(&gp[4 * cg + 1], hq.y);
            atomicAdd(&gp[4 * cg + 2], hq.z);
            atomicAdd(&gp[4 * cg + 3], hq.w);
        } else {
            *(float4*)(hout + (size_t)n * 32 + 4 * cg) = hq;
        }
    }
    if (LAST) {
        __syncthreads();
        if (threadIdx.x < 32)
            atomicAdd(&part_g[(blockIdx.x & 63) * 32 + threadIdx.x], gp[threadIdx.x]);
    }
}

// ---------------- head MLP: reduce part_g[64][32]; 32 -> 256 -> 32 -> 2 ----------------

__global__ void k_head(const float* __restrict__ part_g,
                       const float* __restrict__ W1, const float* __restrict__ b1,
                       const float* __restrict__ W2, const float* __restrict__ b2,
                       const float* __restrict__ W3, const float* __restrict__ b3,
                       float* __restrict__ out) {
    __shared__ float red[256];
    __shared__ float gv[32];
    __shared__ float h1[256];
    __shared__ float h2[32];
    int t = threadIdx.x;
    int col = t & 31, r = t >> 5;
    float lsum = 0.f;
#pragma unroll
    for (int k = 0; k < 8; ++k) lsum += part_g[(r + 8 * k) * 32 + col];
    red[t] = lsum; __syncthreads();
    if (r < 4) red[t] += red[t + 128];
    __syncthreads();
    if (r < 2) red[t] += red[t + 64];
    __syncthreads();
    if (r < 1) gv[col] = (red[t] + red[t + 32]) * (1.0f / NN);
    __syncthreads();
    float acc = b1[t];
#pragma unroll 8
    for (int k = 0; k < 32; ++k) acc += gv[k] * W1[k * 256 + t];
    h1[t] = acc > 0.f ? acc : NEG * acc;
    __syncthreads();
    if (t < 32) {
        float a = b2[t];
        for (int k = 0; k < 256; ++k) a += h1[k] * W2[k * 32 + t];
        h2[t] = a > 0.f ? a : NEG * a;
    }
    __syncthreads();
    if (t < 2) {
        float a = b3[t];
#pragma unroll
        for (int k = 0; k < 32; ++k) a += h2[k] * W3[k * 2 + t];
        out[t] = a;
    }
}

// ---------------- host ----------------

static inline size_t alignup(size_t x) { return (x + 255) & ~size_t(255); }

extern "C" void kernel_launch(void* const* d_in, const int* in_sizes, int n_in,
                              void* d_out, int out_size, void* d_ws, size_t ws_size,
                              hipStream_t stream) {
    const float* x     = (const float*)d_in[0];
    const int*   eidx  = (const int*)d_in[1];
    const float* eattr = (const float*)d_in[2];
    const float* Wl    = (const float*)d_in[4];
    const float* bl    = (const float*)d_in[5];
    const float* Wr    = (const float*)d_in[6];
    const float* br    = (const float*)d_in[7];
    const float* att   = (const float*)d_in[8];
    const float* We    = (const float*)d_in[9];
    const float* cb    = (const float*)d_in[10];
    const float* lW    = (const float*)d_in[11];
    const float* lb    = (const float*)d_in[12];
    const float* bsc   = (const float*)d_in[13];
    const float* bsh   = (const float*)d_in[14];
    const float* W1    = (const float*)d_in[15];
    const float* b1    = (const float*)d_in[16];
    const float* W2    = (const float*)d_in[17];
    const float* b2    = (const float*)d_in[18];
    const float* W3    = (const float*)d_in[19];
    const float* b3    = (const float*)d_in[20];

    const int* srcp = eidx;
    const int* dstp = eidx + EE;

    char* ws = (char*)d_ws;
    size_t off = 0;
    float* xl = (float*)(ws + off); off += alignup((size_t)NN * HC * 4);
    float* xr = (float*)(ws + off); off += alignup((size_t)NN * HC * 4);
    float* hA = (float*)(ws + off); off += alignup((size_t)NN * FF * 4);
    float* hB = (float*)(ws + off); off += alignup((size_t)NN * FF * 4);

    // bucket layout: pairsB, then a contiguous zeroed region {cntB, part_g}
    size_t boff = off;
    int2*  pairsB = (int2*) (ws + boff); boff += alignup((size_t)NN * CAP * 8);
    int*   cntB   = (int*)  (ws + boff); size_t z0 = boff; boff += alignup((size_t)NN * 4);
    float* partGB = (float*)(ws + boff); boff += alignup(64 * 32 * 4);
    const size_t zlenB = boff - z0;
    const bool bucket = (ws_size >= boff);

    const float* cur = x;
    float* hbuf[2] = {hA, hB};

    if (bucket) {
        hipMemsetAsync(cntB, 0, zlenB, stream);
        k_bucket<<<(EE + 255) / 256, 256, 0, stream>>>(srcp, dstp, eattr, cntB, pairsB);
        for (int i = 0; i < 3; ++i) {
            k_dual_linear<<<768, 256, 0, stream>>>(cur, Wl + i * FF * HC, bl + i * HC,
                                                   Wr + i * FF * HC, br + i * HC, xl, xr);
            if (i < 2)
                k_gat_mlp<true, false><<<NN / 8, 256, 0, stream>>>(
                    xl, xr, cntB, pairsB, att + i * HC, We + i * HC, cb + i * HC,
                    lW + i * HC * FF, lb + i * FF, bsc + i * FF, bsh + i * FF,
                    hbuf[i & 1], partGB);
            else
                k_gat_mlp<true, true><<<NN / 8, 256, 0, stream>>>(
                    xl, xr, cntB, pairsB, att + i * HC, We + i * HC, cb + i * HC,
                    lW + i * HC * FF, lb + i * FF, bsc + i * FF, bsh + i * FF,
                    hbuf[i & 1], partGB);
            cur = hbuf[i & 1];
        }
        k_head<<<1, 256, 0, stream>>>(partGB, W1, b1, W2, b2, W3, b3, (float*)d_out);
    } else {
        // CSR fallback: hist + 3-kernel scan + scatter; zero region {deg, fill, part, part_g}
        size_t coff = off;
        int2*  pairsC = (int2*) (ws + coff); coff += alignup((size_t)EE * 8);
        int*   rowptr = (int*)  (ws + coff); coff += alignup((size_t)(NN + 1) * 4);
        int*   deg    = (int*)  (ws + coff); size_t z1 = coff; coff += alignup((size_t)NN * 4);
        int*   fill   = (int*)  (ws + coff); coff += alignup((size_t)NN * 4);
        int*   part   = (int*)  (ws + coff); coff += alignup(64 * 4);
        float* partGC = (float*)(ws + coff); coff += alignup(64 * 32 * 4);
        const size_t zlenC = coff - z1;

        hipMemsetAsync(deg, 0, zlenC, stream);
        const int nChunk = (NN + 1023) / 1024;  // 49
        k_hist<<<(EE + 255) / 256, 256, 0, stream>>>(dstp, deg);
        k_scan1<<<nChunk, 256, 0, stream>>>(deg, part);
        k_scan2<<<1, 64, 0, stream>>>(part, nChunk);
        k_scan3<<<nChunk, 256, 0, stream>>>(deg, part, rowptr);
        k_scatter<<<(EE + 255) / 256, 256, 0, stream>>>(srcp, dstp, eattr, rowptr, fill, pairsC);

        for (int i = 0; i < 3; ++i) {
            k_dual_linear<<<768, 256, 0, stream>>>(cur, Wl + i * FF * HC, bl + i * HC,
                                                   Wr + i * FF * HC, br + i * HC, xl, xr);
            if (i < 2)
                k_gat_mlp<false, false><<<NN / 8, 256, 0, stream>>>(
                    xl, xr, rowptr, pairsC, att + i * HC, We + i * HC, cb + i * HC,
                    lW + i * HC * FF, lb + i * FF, bsc + i * FF, bsh + i * FF,
                    hbuf[i & 1], partGC);
            else
                k_gat_mlp<false, true><<<NN / 8, 256, 0, stream>>>(
                    xl, xr, rowptr, pairsC, att + i * HC, We + i * HC, cb + i * HC,
                    lW + i * HC * FF, lb + i * FF, bsc + i * FF, bsh + i * FF,
                    hbuf[i & 1], partGC);
            cur = hbuf[i & 1];
        }
        k_head<<<1, 256, 0, stream>>>(partGC, W1, b1, W2, b2, W3, b3, (float*)d_out);
    }
}